// Round 12
// baseline (326.393 us; speedup 1.0000x reference)
//
#include <hip/hip_runtime.h>
#include <hip/hip_bf16.h>

typedef __bf16 bf16x8 __attribute__((ext_vector_type(8)));
typedef float f32x4 __attribute__((ext_vector_type(4)));
typedef unsigned short u16x8 __attribute__((ext_vector_type(8)));

static __device__ __forceinline__ unsigned short f2bf(float f){
  unsigned int u = __float_as_uint(f);
  u += 0x7fffu + ((u >> 16) & 1u);   // round-to-nearest-even
  return (unsigned short)(u >> 16);
}

static __device__ __forceinline__ u16x8 cvt8(const float4& a, const float4& b){
  u16x8 r;
  r[0]=f2bf(a.x); r[1]=f2bf(a.y); r[2]=f2bf(a.z); r[3]=f2bf(a.w);
  r[4]=f2bf(b.x); r[5]=f2bf(b.y); r[6]=f2bf(b.z); r[7]=f2bf(b.w);
  return r;
}

static __device__ __forceinline__ void gload16(const void* g, void* l){
  __builtin_amdgcn_global_load_lds(
      (const __attribute__((address_space(1))) unsigned int*)g,
      (__attribute__((address_space(3))) unsigned int*)l, 16, 0, 0);
}

// ============ 2-phase 256^2 GEMM (m230-V0 structure): C = epi(A @ B^T) =============
// A:[M][K] bf16, B:[N][K] bf16, K mult of 64 within each chunk. BK=64.
// 8 waves (2M x 4N), wave tile 128x64, acc[8][4]. Double-buffered 128KB LDS,
// distance-1 prefetch, counted vmcnt(8) steady / vmcnt(0) last (never drain mid-loop).
// BK=64 -> 128B rows -> G4 16-way conflict; fixed by XOR swizzle (r11-verified pair):
//   stage: pre-swizzled SOURCE granule (lane&7)^(lane>>3) into linear wave-owned chunks
//   read : granule slot g^(r&7)  (frag == one 16B granule -> single b128, 2 lanes/bank)
// EPI 0: Cf=acc+bias  EPI 1: atomicAdd  EPI 2: Cbf=bf16(tanh(acc+bias))
template<int EPI>
__global__ __launch_bounds__(512, 1) void gemm_p2(
    const unsigned short* __restrict__ A, const unsigned short* __restrict__ Bw,
    const float* __restrict__ bias,
    float* __restrict__ Cf, unsigned short* __restrict__ Cbf,
    int M, int N, int K, int kchunk)
{
  constexpr int BK = 64;
  constexpr int ABYTES = 256 * BK * 2;   // 32KB per operand
  constexpr int BUFB   = 2 * ABYTES;     // 64KB per buffer
  __shared__ char smem[2 * BUFB];        // 128KB

  const int tid = threadIdx.x, lane = tid & 63, wave = tid >> 6;
  const int wr = wave >> 2, wc = wave & 3;          // 2 x 4 wave grid
  const int bm0 = blockIdx.y * 256, bn0 = blockIdx.x * 256;
  const int k0  = blockIdx.z * kchunk;
  const int kend = min(K, k0 + kchunk);
  const int nk   = (kend - k0) / BK;                // exact: chunks mult of 64
  const int fr = lane & 15, fq = lane >> 4;

  // staging: chunk = 1KB = 8 rows x 128B; wave w owns chunks w*4+c (c=0..3) per operand
  const int srow  = lane >> 3;                      // row-in-chunk == r&7
  const int scol  = ((lane & 7) ^ (lane >> 3)) * 8; // pre-swizzled source granule (elems)

  auto stage = [&](int t){
    char* base = smem + (t & 1) * BUFB;
    const int kk = k0 + t * BK;
    #pragma unroll
    for (int c = 0; c < 4; c++) {
      const int r = min(bm0 + wave * 32 + c * 8 + srow, M - 1);
      gload16(A + (size_t)r * K + kk + scol, base + (wave * 4 + c) * 1024);
    }
    #pragma unroll
    for (int c = 0; c < 4; c++) {
      const int r = min(bn0 + wave * 32 + c * 8 + srow, N - 1);
      gload16(Bw + (size_t)r * K + kk + scol, base + ABYTES + (wave * 4 + c) * 1024);
    }
  };

  stage(0);
  if (nk > 1) stage(1);

  f32x4 acc[8][4] = {};

  for (int t = 0; t < nk; ++t) {
    if (t < nk - 1) asm volatile("s_waitcnt vmcnt(8)" ::: "memory");
    else            asm volatile("s_waitcnt vmcnt(0)" ::: "memory");
    __builtin_amdgcn_s_barrier();                    // tile t visible to all waves
    __builtin_amdgcn_sched_barrier(0);

    const char* lA = smem + (t & 1) * BUFB;
    const char* lB = lA + ABYTES;

    u16x8 af0[8], af1[8], bg0[4], bg1[4];
    #pragma unroll
    for (int i = 0; i < 8; i++) {                    // A rows, ksub 0 (granule fq) & 1 (4+fq)
      const int r = wr * 128 + i * 16 + fr;
      const char* rp = lA + r * 128;
      af0[i] = *(const u16x8*)(rp + ((fq       ^ (r & 7)) << 4));
      af1[i] = *(const u16x8*)(rp + (((4 + fq) ^ (r & 7)) << 4));
    }
    #pragma unroll
    for (int j = 0; j < 4; j++) {                    // B rows
      const int r = wc * 64 + j * 16 + fr;
      const char* rp = lB + r * 128;
      bg0[j] = *(const u16x8*)(rp + ((fq       ^ (r & 7)) << 4));
      bg1[j] = *(const u16x8*)(rp + (((4 + fq) ^ (r & 7)) << 4));
    }
    asm volatile("s_waitcnt lgkmcnt(0)" ::: "memory");
    __builtin_amdgcn_sched_barrier(0);
    __builtin_amdgcn_s_barrier();                    // all waves done reading buf t&1
    if (t + 2 < nk) stage(t + 2);                    // refill freed buffer (DMA ∥ MFMA)

    #pragma unroll
    for (int i = 0; i < 8; i++)
      #pragma unroll
      for (int j = 0; j < 4; j++)
        acc[i][j] = __builtin_amdgcn_mfma_f32_16x16x32_bf16(
            __builtin_bit_cast(bf16x8, af0[i]), __builtin_bit_cast(bf16x8, bg0[j]),
            acc[i][j], 0, 0, 0);
    #pragma unroll
    for (int i = 0; i < 8; i++)
      #pragma unroll
      for (int j = 0; j < 4; j++)
        acc[i][j] = __builtin_amdgcn_mfma_f32_16x16x32_bf16(
            __builtin_bit_cast(bf16x8, af1[i]), __builtin_bit_cast(bf16x8, bg1[j]),
            acc[i][j], 0, 0, 0);
  }

  #pragma unroll
  for (int i = 0; i < 8; i++)
    #pragma unroll
    for (int j = 0; j < 4; j++)
      #pragma unroll
      for (int r = 0; r < 4; r++) {
        int row = bm0 + wr * 128 + i * 16 + fq * 4 + r;
        int col = bn0 + wc * 64 + j * 16 + fr;
        if (row < M && col < N) {
          float v = acc[i][j][r];
          if constexpr (EPI == 0) {
            Cf[(size_t)row * N + col] = v + (bias ? bias[col] : 0.0f);
          } else if constexpr (EPI == 1) {
            atomicAdd(&Cf[(size_t)row * N + col], v);
          } else {
            Cbf[(size_t)row * N + col] = f2bf(tanhf(v + bias[col]));
          }
        }
      }
}

// ================= SMALL-GEMM kernel: m97-form 128x128, simple 2-barrier ============
template<int EPI>
__global__ __launch_bounds__(256) void gemm_sm(
    const unsigned short* __restrict__ A, const unsigned short* __restrict__ Bw,
    const float* __restrict__ bias,
    float* __restrict__ Cf, unsigned short* __restrict__ Cbf,
    int M, int N, int K, int kchunk)
{
  constexpr int BM = 128, BN = 128, BK = 32;
  __shared__ unsigned short lds[(BM + BN) * BK];      // 16 KB
  unsigned short* lA = lds;
  unsigned short* lB = lds + BM * BK;

  const int tid  = threadIdx.x, lane = tid & 63, wave = tid >> 6;
  const int bm0  = blockIdx.y * BM, bn0 = blockIdx.x * BN;
  const int k0   = blockIdx.z * kchunk;
  const int kend = min(K, k0 + kchunk);
  const int fr = lane & 15, fq = lane >> 4;
  const int wm = (wave >> 1) * 64, wn = (wave & 1) * 64;

  const bool isA  = wave < 2;
  const int cbase = (wave & 1) * 4;
  const int srow  = lane >> 2, scol = (lane & 3) * 8;
  const unsigned short* G = isA ? A : Bw;
  const int glim = (isA ? M : N) - 1;
  const int g0   = isA ? bm0 : bn0;
  unsigned short* ldst = isA ? lA : lB;

  f32x4 acc[4][4] = {};

  for (int kk = k0; kk < kend; kk += BK) {
    #pragma unroll
    for (int c = 0; c < 4; c++) {
      const int ch = cbase + c;
      const int r = min(g0 + ch * 16 + srow, glim);
      gload16(G + (size_t)r * K + kk + scol, (char*)ldst + ch * 1024);
    }
    __syncthreads();
    u16x8 af[4], bg[4];
    #pragma unroll
    for (int i = 0; i < 4; i++) af[i] = *(const u16x8*)&lA[(wm + i*16 + fr) * BK + fq * 8];
    #pragma unroll
    for (int j = 0; j < 4; j++) bg[j] = *(const u16x8*)&lB[(wn + j*16 + fr) * BK + fq * 8];
    #pragma unroll
    for (int i = 0; i < 4; i++)
      #pragma unroll
      for (int j = 0; j < 4; j++)
        acc[i][j] = __builtin_amdgcn_mfma_f32_16x16x32_bf16(
            __builtin_bit_cast(bf16x8, af[i]),
            __builtin_bit_cast(bf16x8, bg[j]),
            acc[i][j], 0, 0, 0);
    __syncthreads();
  }

  #pragma unroll
  for (int i = 0; i < 4; i++)
    #pragma unroll
    for (int j = 0; j < 4; j++)
      #pragma unroll
      for (int r = 0; r < 4; r++) {
        int row = bm0 + wm + i*16 + fq*4 + r;
        int col = bn0 + wn + j*16 + fr;
        if (row < M && col < N) {
          float v = acc[i][j][r];
          if constexpr (EPI == 0) {
            Cf[(size_t)row * N + col] = v + (bias ? bias[col] : 0.0f);
          } else if constexpr (EPI == 1) {
            atomicAdd(&Cf[(size_t)row * N + col], v);
          } else {
            Cbf[(size_t)row * N + col] = f2bf(tanhf(v + bias[col]));
          }
        }
      }
}

// ---------------- fp32 -> bf16 conversion (up to 4 flat segments) ----------------
__global__ __launch_bounds__(256) void cvt4_kernel(
    const float* __restrict__ s0, unsigned short* __restrict__ d0, int n0,
    const float* __restrict__ s1, unsigned short* __restrict__ d1, int n1,
    const float* __restrict__ s2, unsigned short* __restrict__ d2, int n2,
    const float* __restrict__ s3, unsigned short* __restrict__ d3, int n3)
{
  int i = (blockIdx.x * 256 + threadIdx.x) * 8;
  const float* s; unsigned short* d;
  if (i < n0)            { s = s0; d = d0; }
  else if ((i -= n0) < n1) { s = s1; d = d1; }
  else if ((i -= n1) < n2) { s = s2; d = d2; }
  else if ((i -= n2) < n3) { s = s3; d = d3; }
  else return;
  const float4* q = (const float4*)(s + i);
  *(u16x8*)(d + i) = cvt8(q[0], q[1]);
}

// fp32 [rows][scols] -> bf16 [rows][dcols], zero-padded (dcols mult of 8)
__global__ __launch_bounds__(256) void cvtpad_kernel(
    const float* __restrict__ src, unsigned short* __restrict__ dst,
    int rows, int scols, int dcols)
{
  int i8 = blockIdx.x * 256 + threadIdx.x;
  int c8 = dcols / 8;
  if (i8 >= rows * c8) return;
  int r = i8 / c8, c0 = (i8 % c8) * 8;
  const float* s = src + (size_t)r * scols;
  u16x8 o;
  #pragma unroll
  for (int e = 0; e < 8; e++) { int c = c0 + e; o[e] = (c < scols) ? f2bf(s[c]) : (unsigned short)0; }
  *(u16x8*)(dst + (size_t)r * dcols + c0) = o;
}

// ---------------- elementwise / reduction kernels ----------------
// y = bf16(x*dm) padded to D0p cols (pad = 0); ninv = 1/max(||x||,1e-12)
__global__ __launch_bounds__(256) void ynorm_kernel(
    const float* __restrict__ x, const float* __restrict__ dm,
    unsigned short* __restrict__ y, float* __restrict__ ninv, int D0, int D0p)
{
  const int b = blockIdx.x, tid = threadIdx.x;
  const float4* x4 = (const float4*)(x + (size_t)b * D0);
  const float4* d4 = (const float4*)(dm + (size_t)b * D0);
  ushort4* y4 = (ushort4*)(y + (size_t)b * D0p);
  const int n4 = D0 / 4, n4p = D0p / 4;
  float ss = 0.f;
  for (int i = tid; i < n4p; i += 256) {
    ushort4 o;
    if (i < n4) {
      float4 xv = x4[i], dv = d4[i];
      ss += xv.x*xv.x + xv.y*xv.y + xv.z*xv.z + xv.w*xv.w;
      o.x = f2bf(xv.x*dv.x); o.y = f2bf(xv.y*dv.y);
      o.z = f2bf(xv.z*dv.z); o.w = f2bf(xv.w*dv.w);
    } else {
      o.x = o.y = o.z = o.w = 0;
    }
    y4[i] = o;
  }
  #pragma unroll
  for (int off = 32; off > 0; off >>= 1) ss += __shfl_down(ss, off);
  __shared__ float wsum[4];
  if ((tid & 63) == 0) wsum[tid >> 6] = ss;
  __syncthreads();
  if (tid == 0) {
    float t = wsum[0] + wsum[1] + wsum[2] + wsum[3];
    ninv[b] = 1.0f / fmaxf(sqrtf(t), 1e-12f);
  }
}

__global__ __launch_bounds__(256) void stats_kernel(
    const float* __restrict__ proj, const int* __restrict__ ids,
    const float* __restrict__ bi, const float* __restrict__ eps,
    float* __restrict__ prior, int T)
{
  const int b = blockIdx.x, l = threadIdx.x;
  __shared__ int sid[256];
  if (l < T) sid[l] = ids[b * T + l];
  __syncthreads();
  float s1 = 0.f, s2 = 0.f;
  #pragma unroll 4
  for (int t = 0; t < T; t++) {
    float p = proj[(size_t)sid[t] * 256 + l];
    s1 += p; s2 += p * p;
  }
  float var = fmaxf((s2 - s1 * s1 / (float)T) / (float)(T - 1), 0.f);
  float dev = sqrtf(var);
  float mean = s1 / (float)T + bi[l];
  prior[b * 256 + l] = mean + sqrtf(dev) * eps[b * 256 + l];
}

__global__ __launch_bounds__(256) void epi1_kernel(
    const float* __restrict__ C1, const float* __restrict__ ninv,
    const float* __restrict__ be1, unsigned short* __restrict__ h)
{
  int i = blockIdx.x * 256 + threadIdx.x;
  int b = i >> 10, n = i & 1023;
  h[i] = f2bf(tanhf(ninv[b] * C1[i] + be1[n]));
}

__global__ __launch_bounds__(256) void z_kernel(
    const float* __restrict__ gp, const float* __restrict__ prior,
    const float* __restrict__ be2,
    float* __restrict__ out_mu, float* __restrict__ out_lv,
    unsigned short* __restrict__ z)
{
  int i = blockIdx.x * 256 + threadIdx.x;
  int b = i >> 8, l = i & 255;
  float mu = gp[b * 512 + l]       + be2[l];
  float lv = gp[b * 512 + 256 + l] + be2[256 + l];
  out_mu[i] = mu;
  out_lv[i] = lv;
  z[i] = f2bf(prior[i] * expf(0.5f * lv) + mu);
}

extern "C" void kernel_launch(void* const* d_in, const int* in_sizes, int n_in,
                              void* d_out, int out_size, void* d_ws, size_t ws_size,
                              hipStream_t stream)
{
  const float* x     = (const float*)d_in[0];
  const int*   ids   = (const int*)  d_in[1];
  const float* embed = (const float*)d_in[2];
  const float* Wi    = (const float*)d_in[3];
  const float* bi    = (const float*)d_in[4];
  const float* We1   = (const float*)d_in[5];
  const float* be1   = (const float*)d_in[6];
  const float* We2   = (const float*)d_in[7];
  const float* be2   = (const float*)d_in[8];
  const float* Wd1   = (const float*)d_in[9];
  const float* bd1   = (const float*)d_in[10];
  const float* Wd2   = (const float*)d_in[11];
  const float* bd2   = (const float*)d_in[12];
  const float* dm    = (const float*)d_in[13];
  const float* eps   = (const float*)d_in[14];

  constexpr int B = 512, T = 200, V = 3356, E = 1128, Ep = 1152,
                D0 = 20000, D0p = 20032, H = 1024, L = 256;

  char* w = (char*)d_ws;
  auto carve = [&](size_t bytes) { char* p = w; w += (bytes + 255) & ~(size_t)255; return p; };
  unsigned short* We1b  = (unsigned short*)carve((size_t)H * D0p * 2);   // 41 MB (padded K)
  unsigned short* Wd2b  = (unsigned short*)carve((size_t)D0 * H * 2);    // 41 MB
  unsigned short* We2b  = (unsigned short*)carve((size_t)2 * L * H * 2);
  unsigned short* Wd1b  = (unsigned short*)carve((size_t)H * L * 2);
  unsigned short* embedb= (unsigned short*)carve((size_t)V * Ep * 2);    // 7.7 MB
  unsigned short* Wib   = (unsigned short*)carve((size_t)L * Ep * 2);
  float*          proj  = (float*)         carve((size_t)V * L * 4);     // 3.4 MB
  unsigned short* y     = (unsigned short*)carve((size_t)B * D0p * 2);   // 20.5 MB
  float*          C1    = (float*)         carve((size_t)B * H * 4);
  unsigned short* h     = (unsigned short*)carve((size_t)B * H * 2);
  float*          gp    = (float*)         carve((size_t)B * 2 * L * 4);
  float*          prior = (float*)         carve((size_t)B * L * 4);
  unsigned short* z     = (unsigned short*)carve((size_t)B * L * 2);
  unsigned short* hd    = (unsigned short*)carve((size_t)B * H * 2);
  float*          ninv  = (float*)         carve((size_t)B * 4);

  float* out_recon = (float*)d_out;
  float* out_mu    = out_recon + (size_t)B * D0;
  float* out_lv    = out_mu + (size_t)B * L;

  // weights -> bf16: Wd2/We2/Wd1 flat; We1 padded 20000->20032; embed/Wi padded to 1152
  {
    const int n0 = D0 * H, n1 = 2 * L * H, n2 = H * L;
    cvt4_kernel<<<(n0 + n1 + n2) / (8 * 256), 256, 0, stream>>>(
        Wd2, Wd2b, n0, We2, We2b, n1, Wd1, Wd1b, n2, Wd1, Wd1b, 0);
  }
  cvtpad_kernel<<<(H * (D0p/8) + 255) / 256, 256, 0, stream>>>(We1, We1b, H, D0, D0p);
  cvtpad_kernel<<<(V * (Ep/8) + 255) / 256, 256, 0, stream>>>(embed, embedb, V, E, Ep);
  cvtpad_kernel<<<(L * (Ep/8) + 255) / 256, 256, 0, stream>>>(Wi, Wib, L, E, Ep);

  // y = bf16(x*dm) (zero-padded to D0p), ninv = 1/||x||
  ynorm_kernel<<<B, 256, 0, stream>>>(x, dm, y, ninv, D0, D0p);

  // proj = embedb @ Wib^T  (M=3356, N=256, K=1152), split-K=4  [small kernel]
  hipMemsetAsync(proj, 0, (size_t)V * L * 4, stream);
  gemm_sm<1><<<dim3(2, 27, 4), 256, 0, stream>>>(
      embedb, Wib, nullptr, proj, nullptr, V, L, Ep, 288);
  // prior from gathered stats (adds bi)
  stats_kernel<<<B, 256, 0, stream>>>(proj, ids, bi, eps, prior, T);

  // GEMM1: C1 = y @ We1b^T  (M=512, N=1024, K=20032), 256^2 2-phase, split-K=32
  hipMemsetAsync(C1, 0, (size_t)B * H * 4, stream);
  gemm_p2<1><<<dim3(4, 2, 32), 512, 0, stream>>>(
      y, We1b, nullptr, C1, nullptr, B, H, D0p, 640);
  // h = tanh(ninv*C1 + be1)
  epi1_kernel<<<(B * H) / 256, 256, 0, stream>>>(C1, ninv, be1, h);

  // gparams = h @ We2b^T (+be2 in z_kernel)  (M=512, N=512, K=1024), split-K=4  [small]
  hipMemsetAsync(gp, 0, (size_t)B * 2 * L * 4, stream);
  gemm_sm<1><<<dim3(4, 4, 4), 256, 0, stream>>>(
      h, We2b, nullptr, gp, nullptr, B, 2 * L, H, 256);
  // mu/logvar out, z
  z_kernel<<<(B * L) / 256, 256, 0, stream>>>(gp, prior, be2, out_mu, out_lv, z);

  // hd = tanh(z @ Wd1b^T + bd1)  (M=512, N=1024, K=256)  [small]
  gemm_sm<2><<<dim3(8, 4, 1), 256, 0, stream>>>(
      z, Wd1b, bd1, nullptr, hd, B, H, L, 256);
  // recon = hd @ Wd2b^T + bd2   (M=512, N=20000, K=1024), 256^2 2-phase
  gemm_p2<0><<<dim3(79, 2, 1), 512, 0, stream>>>(
      hd, Wd2b, bd2, out_recon, nullptr, B, D0, H, 1024);
}

// Round 13
// 267.720 us; speedup vs baseline: 1.2192x; 1.2192x over previous
//
#include <hip/hip_runtime.h>
#include <hip/hip_bf16.h>

typedef __bf16 bf16x8 __attribute__((ext_vector_type(8)));
typedef float f32x4 __attribute__((ext_vector_type(4)));
typedef unsigned short u16x8 __attribute__((ext_vector_type(8)));

static __device__ __forceinline__ unsigned short f2bf(float f){
  unsigned int u = __float_as_uint(f);
  u += 0x7fffu + ((u >> 16) & 1u);   // round-to-nearest-even
  return (unsigned short)(u >> 16);
}

static __device__ __forceinline__ u16x8 cvt8(const float4& a, const float4& b){
  u16x8 r;
  r[0]=f2bf(a.x); r[1]=f2bf(a.y); r[2]=f2bf(a.z); r[3]=f2bf(a.w);
  r[4]=f2bf(b.x); r[5]=f2bf(b.y); r[6]=f2bf(b.z); r[7]=f2bf(b.w);
  return r;
}

static __device__ __forceinline__ void gload16(const void* g, void* l){
  __builtin_amdgcn_global_load_lds(
      (const __attribute__((address_space(1))) unsigned int*)g,
      (__attribute__((address_space(3))) unsigned int*)l, 16, 0, 0);
}

// T1: XCD-aware bijective block remap (m204 variant). MI355X has 8 XCDs with private
// L2s; default dispatch round-robins consecutive ids across XCDs. This remap gives
// each XCD a CONTIGUOUS chunk of logical tile ids, so consecutive bx tiles (which
// share an A panel) hit the same L2. Bijective for any nwg (gemm4: 628 % 8 = 4).
static __device__ __forceinline__ int xcd_remap(int o, int nwg){
  const int NX = 8;
  int q = nwg / NX, r = nwg % NX;
  int xcd = o % NX, pos = o / NX;
  return (xcd < r ? xcd * (q + 1) : r * (q + 1) + (xcd - r) * q) + pos;
}

// ---------------- pipelined bf16 GEMM: C[m,n] = epi( sum_k A[m,k]*B[n,k] )
// A:[M][K] bf16, B:[N][K] bf16, row-major. BM=BN=128, BK=32, 4 waves (2x2 of 64x64).
// r6-verified schedule: TRIPLE-buffered LDS, prefetch distance 2, counted
// s_waitcnt vmcnt(8/4/0), raw s_barrier. Per K-step: wait(tile t) -> barrier ->
// ds_read -> lgkmcnt(0) -> barrier -> stage(t+3) into freed buffer -> 16 MFMA.
// EPI 0: Cf = acc + bias(optional)  EPI 1: atomicAdd(Cf, acc)  EPI 2: Cbf = bf16(tanh(acc+bias))
template<int EPI>
__global__ __launch_bounds__(256) void gemm_bf(
    const unsigned short* __restrict__ A, const unsigned short* __restrict__ Bw,
    const float* __restrict__ bias,
    float* __restrict__ Cf, unsigned short* __restrict__ Cbf,
    int M, int N, int K, int kchunk)
{
  constexpr int BM = 128, BN = 128, BK = 32, BUF = (BM + BN) * BK;
  __shared__ unsigned short lds[3 * BUF];             // 3 x 16 KB

  // T1 remap: consecutive logical ids (fastest dim = x) chunked per XCD
  const int gx = gridDim.x, gy = gridDim.y;
  const int nwg = gx * gy * gridDim.z;
  int o = blockIdx.x + gx * (blockIdx.y + gy * blockIdx.z);
  int v = xcd_remap(o, nwg);
  const int bx = v % gx; v /= gx;
  const int by = v % gy; const int bz = v / gy;

  const int tid  = threadIdx.x, lane = tid & 63, wave = tid >> 6;
  const int bm0  = by * BM, bn0 = bx * BN;
  const int k0   = bz * kchunk;
  const int kend = min(K, k0 + kchunk);               // kchunk multiple of 32 everywhere
  const int fr = lane & 15, fq = lane >> 4;
  const int wm = (wave >> 1) * 64, wn = (wave & 1) * 64;

  // staging: waves 0,1 -> A chunks 0..3 / 4..7; waves 2,3 -> B likewise.
  // chunk = 1KB = 16 rows of [128][32] bf16; lane l -> dest base + l*16
  const bool isA  = wave < 2;
  const int cbase = (wave & 1) * 4;
  const int srow  = lane >> 2, scol = (lane & 3) * 8;
  const unsigned short* G = isA ? A : Bw;
  const int glim = (isA ? M : N) - 1;
  const int g0   = isA ? bm0 : bn0;
  const int loff = isA ? 0 : BM * BK;

  const int nk = (kend - k0) / BK;                    // exact (kchunk mult of 32)

  auto stage = [&](int buf, int t){
    unsigned short* dst = lds + buf * BUF + loff;
    const int kk = k0 + t * BK;
    #pragma unroll
    for (int c = 0; c < 4; c++) {
      const int ch = cbase + c;
      const int r = min(g0 + ch * 16 + srow, glim);   // clamp; epilogue masks
      gload16(G + (size_t)r * K + kk + scol, (char*)dst + ch * 1024);
    }
  };

  if (nk > 0) stage(0, 0);
  if (nk > 1) stage(1, 1);
  if (nk > 2) stage(2, 2);

  f32x4 acc[4][4] = {};
  int cur = 0;                                        // = t % 3

  for (int t = 0; t < nk; ++t) {
    const int rem = nk - t - 1;                       // stages in flight beyond t
    if (rem >= 2)      asm volatile("s_waitcnt vmcnt(8)" ::: "memory");
    else if (rem == 1) asm volatile("s_waitcnt vmcnt(4)" ::: "memory");
    else               asm volatile("s_waitcnt vmcnt(0)" ::: "memory");
    __builtin_amdgcn_s_barrier();                     // tile t visible to all waves
    __builtin_amdgcn_sched_barrier(0);

    const unsigned short* lA = lds + cur * BUF;
    const unsigned short* lB = lA + BM * BK;
    u16x8 af[4], bg[4];
    #pragma unroll
    for (int i = 0; i < 4; i++) af[i] = *(const u16x8*)&lA[(wm + i*16 + fr) * BK + fq * 8];
    #pragma unroll
    for (int j = 0; j < 4; j++) bg[j] = *(const u16x8*)&lB[(wn + j*16 + fr) * BK + fq * 8];
    asm volatile("s_waitcnt lgkmcnt(0)" ::: "memory"); // my reads complete (regs)
    __builtin_amdgcn_sched_barrier(0);
    __builtin_amdgcn_s_barrier();                     // all waves done reading buf cur
    if (t + 3 < nk) stage(cur, t + 3);                // refill freed buffer (DMA ∥ MFMA)

    #pragma unroll
    for (int i = 0; i < 4; i++)
      #pragma unroll
      for (int j = 0; j < 4; j++)
        acc[i][j] = __builtin_amdgcn_mfma_f32_16x16x32_bf16(
            __builtin_bit_cast(bf16x8, af[i]),
            __builtin_bit_cast(bf16x8, bg[j]),
            acc[i][j], 0, 0, 0);
    cur = (cur == 2) ? 0 : cur + 1;
  }

  #pragma unroll
  for (int i = 0; i < 4; i++)
    #pragma unroll
    for (int j = 0; j < 4; j++)
      #pragma unroll
      for (int r = 0; r < 4; r++) {
        int row = bm0 + wm + i*16 + fq*4 + r;
        int col = bn0 + wn + j*16 + fr;
        if (row < M && col < N) {
          float v2 = acc[i][j][r];
          if constexpr (EPI == 0) {
            Cf[(size_t)row * N + col] = v2 + (bias ? bias[col] : 0.0f);
          } else if constexpr (EPI == 1) {
            atomicAdd(&Cf[(size_t)row * N + col], v2);
          } else {
            Cbf[(size_t)row * N + col] = f2bf(tanhf(v2 + bias[col]));
          }
        }
      }
}

// ---------------- fp32 -> bf16 weight conversion (4 flat segments fused) ----------------
__global__ __launch_bounds__(256) void cvt4_kernel(
    const float* __restrict__ s0, unsigned short* __restrict__ d0, int n0,
    const float* __restrict__ s1, unsigned short* __restrict__ d1, int n1,
    const float* __restrict__ s2, unsigned short* __restrict__ d2, int n2,
    const float* __restrict__ s3, unsigned short* __restrict__ d3, int n3)
{
  int i = (blockIdx.x * 256 + threadIdx.x) * 8;
  const float* s; unsigned short* d;
  if (i < n0)            { s = s0; d = d0; }
  else if ((i -= n0) < n1) { s = s1; d = d1; }
  else if ((i -= n1) < n2) { s = s2; d = d2; }
  else if ((i -= n2) < n3) { s = s3; d = d3; }
  else return;
  const float4* q = (const float4*)(s + i);
  *(u16x8*)(d + i) = cvt8(q[0], q[1]);
}

// fp32 [rows][scols] -> bf16 [rows][dcols], zero-padded (dcols mult of 8)
__global__ __launch_bounds__(256) void cvtpad_kernel(
    const float* __restrict__ src, unsigned short* __restrict__ dst,
    int rows, int scols, int dcols)
{
  int i8 = blockIdx.x * 256 + threadIdx.x;
  int c8 = dcols / 8;
  if (i8 >= rows * c8) return;
  int r = i8 / c8, c0 = (i8 % c8) * 8;
  const float* s = src + (size_t)r * scols;
  u16x8 o;
  #pragma unroll
  for (int e = 0; e < 8; e++) { int c = c0 + e; o[e] = (c < scols) ? f2bf(s[c]) : (unsigned short)0; }
  *(u16x8*)(dst + (size_t)r * dcols + c0) = o;
}

// ---------------- elementwise / reduction kernels ----------------
__global__ __launch_bounds__(256) void ynorm_kernel(
    const float* __restrict__ x, const float* __restrict__ dm,
    unsigned short* __restrict__ y, float* __restrict__ ninv, int D0)
{
  const int b = blockIdx.x, tid = threadIdx.x;
  const float4* x4 = (const float4*)(x + (size_t)b * D0);
  const float4* d4 = (const float4*)(dm + (size_t)b * D0);
  ushort4* y4 = (ushort4*)(y + (size_t)b * D0);
  const int n4 = D0 / 4;
  float ss = 0.f;
  for (int i = tid; i < n4; i += 256) {
    float4 xv = x4[i], dv = d4[i];
    ss += xv.x*xv.x + xv.y*xv.y + xv.z*xv.z + xv.w*xv.w;
    ushort4 o;
    o.x = f2bf(xv.x*dv.x); o.y = f2bf(xv.y*dv.y);
    o.z = f2bf(xv.z*dv.z); o.w = f2bf(xv.w*dv.w);
    y4[i] = o;
  }
  #pragma unroll
  for (int off = 32; off > 0; off >>= 1) ss += __shfl_down(ss, off);
  __shared__ float wsum[4];
  if ((tid & 63) == 0) wsum[tid >> 6] = ss;
  __syncthreads();
  if (tid == 0) {
    float t = wsum[0] + wsum[1] + wsum[2] + wsum[3];
    ninv[b] = 1.0f / fmaxf(sqrtf(t), 1e-12f);
  }
}

__global__ __launch_bounds__(256) void stats_kernel(
    const float* __restrict__ proj, const int* __restrict__ ids,
    const float* __restrict__ bi, const float* __restrict__ eps,
    float* __restrict__ prior, int T)
{
  const int b = blockIdx.x, l = threadIdx.x;
  __shared__ int sid[256];
  if (l < T) sid[l] = ids[b * T + l];
  __syncthreads();
  float s1 = 0.f, s2 = 0.f;
  #pragma unroll 4
  for (int t = 0; t < T; t++) {
    float p = proj[(size_t)sid[t] * 256 + l];
    s1 += p; s2 += p * p;
  }
  float var = fmaxf((s2 - s1 * s1 / (float)T) / (float)(T - 1), 0.f);
  float dev = sqrtf(var);
  float mean = s1 / (float)T + bi[l];
  prior[b * 256 + l] = mean + sqrtf(dev) * eps[b * 256 + l];
}

__global__ __launch_bounds__(256) void epi1_kernel(
    const float* __restrict__ C1, const float* __restrict__ ninv,
    const float* __restrict__ be1, unsigned short* __restrict__ h)
{
  int i = blockIdx.x * 256 + threadIdx.x;
  int b = i >> 10, n = i & 1023;
  h[i] = f2bf(tanhf(ninv[b] * C1[i] + be1[n]));
}

__global__ __launch_bounds__(256) void z_kernel(
    const float* __restrict__ gp, const float* __restrict__ prior,
    const float* __restrict__ be2,
    float* __restrict__ out_mu, float* __restrict__ out_lv,
    unsigned short* __restrict__ z)
{
  int i = blockIdx.x * 256 + threadIdx.x;
  int b = i >> 8, l = i & 255;
  float mu = gp[b * 512 + l]       + be2[l];
  float lv = gp[b * 512 + 256 + l] + be2[256 + l];
  out_mu[i] = mu;
  out_lv[i] = lv;
  z[i] = f2bf(prior[i] * expf(0.5f * lv) + mu);
}

extern "C" void kernel_launch(void* const* d_in, const int* in_sizes, int n_in,
                              void* d_out, int out_size, void* d_ws, size_t ws_size,
                              hipStream_t stream)
{
  const float* x     = (const float*)d_in[0];
  const int*   ids   = (const int*)  d_in[1];
  const float* embed = (const float*)d_in[2];
  const float* Wi    = (const float*)d_in[3];
  const float* bi    = (const float*)d_in[4];
  const float* We1   = (const float*)d_in[5];
  const float* be1   = (const float*)d_in[6];
  const float* We2   = (const float*)d_in[7];
  const float* be2   = (const float*)d_in[8];
  const float* Wd1   = (const float*)d_in[9];
  const float* bd1   = (const float*)d_in[10];
  const float* Wd2   = (const float*)d_in[11];
  const float* bd2   = (const float*)d_in[12];
  const float* dm    = (const float*)d_in[13];
  const float* eps   = (const float*)d_in[14];

  constexpr int B = 512, T = 200, V = 3356, E = 1128, Ep = 1152, D0 = 20000, H = 1024, L = 256;

  char* w = (char*)d_ws;
  auto carve = [&](size_t bytes) { char* p = w; w += (bytes + 255) & ~(size_t)255; return p; };
  unsigned short* We1b  = (unsigned short*)carve((size_t)H * D0 * 2);   // 41 MB
  unsigned short* Wd2b  = (unsigned short*)carve((size_t)D0 * H * 2);   // 41 MB
  unsigned short* We2b  = (unsigned short*)carve((size_t)2 * L * H * 2);
  unsigned short* Wd1b  = (unsigned short*)carve((size_t)H * L * 2);
  unsigned short* embedb= (unsigned short*)carve((size_t)V * Ep * 2);   // 7.7 MB
  unsigned short* Wib   = (unsigned short*)carve((size_t)L * Ep * 2);
  float*          proj  = (float*)         carve((size_t)V * L * 4);    // 3.4 MB
  unsigned short* y     = (unsigned short*)carve((size_t)B * D0 * 2);   // 20.5 MB
  float*          C1    = (float*)         carve((size_t)B * H * 4);
  unsigned short* h     = (unsigned short*)carve((size_t)B * H * 2);
  float*          gp    = (float*)         carve((size_t)B * 2 * L * 4);
  float*          prior = (float*)         carve((size_t)B * L * 4);
  unsigned short* z     = (unsigned short*)carve((size_t)B * L * 2);
  unsigned short* hd    = (unsigned short*)carve((size_t)B * H * 2);
  float*          ninv  = (float*)         carve((size_t)B * 4);

  float* out_recon = (float*)d_out;
  float* out_mu    = out_recon + (size_t)B * D0;
  float* out_lv    = out_mu + (size_t)B * L;

  // weights -> bf16 (one fused streaming pass)
  {
    const int n0 = H * D0, n1 = D0 * H, n2 = 2 * L * H, n3 = H * L;
    const int nblk = (n0 + n1 + n2 + n3) / (8 * 256);
    cvt4_kernel<<<nblk, 256, 0, stream>>>(We1, We1b, n0, Wd2, Wd2b, n1,
                                          We2, We2b, n2, Wd1, Wd1b, n3);
  }
  cvtpad_kernel<<<(V * (Ep/8) + 255) / 256, 256, 0, stream>>>(embed, embedb, V, E, Ep);
  cvtpad_kernel<<<(L * (Ep/8) + 255) / 256, 256, 0, stream>>>(Wi, Wib, L, E, Ep);

  // y = bf16(x*dm), ninv = 1/||x||
  ynorm_kernel<<<B, 256, 0, stream>>>(x, dm, y, ninv, D0);

  // proj = embedb @ Wib^T  (M=3356, N=256, K=1152), split-K=4
  hipMemsetAsync(proj, 0, (size_t)V * L * 4, stream);
  gemm_bf<1><<<dim3(2, 27, 4), 256, 0, stream>>>(
      embedb, Wib, nullptr, proj, nullptr, V, L, Ep, 288);
  // prior from gathered stats (adds bi)
  stats_kernel<<<B, 256, 0, stream>>>(proj, ids, bi, eps, prior, T);

  // GEMM1: C1 = y @ We1b^T  (M=512, N=1024, K=20000), split-K=25
  hipMemsetAsync(C1, 0, (size_t)B * H * 4, stream);
  gemm_bf<1><<<dim3(8, 4, 25), 256, 0, stream>>>(
      y, We1b, nullptr, C1, nullptr, B, H, D0, 800);
  // h = tanh(ninv*C1 + be1)
  epi1_kernel<<<(B * H) / 256, 256, 0, stream>>>(C1, ninv, be1, h);

  // gparams = h @ We2b^T (+be2 in z_kernel)  (M=512, N=512, K=1024), split-K=4
  hipMemsetAsync(gp, 0, (size_t)B * 2 * L * 4, stream);
  gemm_bf<1><<<dim3(4, 4, 4), 256, 0, stream>>>(
      h, We2b, nullptr, gp, nullptr, B, 2 * L, H, 256);
  // mu/logvar out, z
  z_kernel<<<(B * L) / 256, 256, 0, stream>>>(gp, prior, be2, out_mu, out_lv, z);

  // hd = tanh(z @ Wd1b^T + bd1)  (M=512, N=1024, K=256)
  gemm_bf<2><<<dim3(8, 4, 1), 256, 0, stream>>>(
      z, Wd1b, bd1, nullptr, hd, B, H, L, 256);
  // recon = hd @ Wd2b^T + bd2   (M=512, N=20000, K=1024)
  gemm_bf<0><<<dim3(157, 4, 1), 256, 0, stream>>>(
      hd, Wd2b, bd2, out_recon, nullptr, B, D0, H, 1024);
}